// Round 1
// 1285.938 us; speedup vs baseline: 1.0230x; 1.0230x over previous
//
#include <hip/hip_runtime.h>
#include <hip/hip_fp16.h>

#define SQRT_HALF 0.70710678118654752f

typedef _Float16 f16x8 __attribute__((ext_vector_type(8)));
typedef _Float16 f16x4 __attribute__((ext_vector_type(4)));
typedef float    f32x4 __attribute__((ext_vector_type(4)));

#define B_ 64
#define T_ 1024
#define S_ 1024
#define C_ 512
#define E_ 512

// ---------------- GEMM: D[M,N] = A[M,K] @ B[N,K]^T (+epilogue) ----------------
// 128x128 block tile, BK=64, 4 waves of 64x64, mfma_f32_16x16x32_f16.
// Staging: global_load_lds width=16, LINEAR LDS (no pad — required by HW:
// dest is wave-uniform base + lane*16). 16-way ds_read bank conflict is
// measured-null at this 2-barrier structure (T2 regime gate).
// A/B frag layout: elem[j] = T[lane&15][k0 + (lane>>4)*8 + j]
// C/D layout:      acc[i]  = D[(lane>>4)*4 + i][lane&15]
#define BKK 64

__device__ __forceinline__ void gload16(const void* g, void* l)
{
    __builtin_amdgcn_global_load_lds(
        (const __attribute__((address_space(1))) void*)g,
        (__attribute__((address_space(3))) void*)l, 16, 0, 0);
}

template<int EPI>
__launch_bounds__(256, 2)
__global__ void gemm_kernel(const _Float16* __restrict__ Abase,
                            const _Float16* __restrict__ Bbase,
                            void* __restrict__ Dbase,
                            const float* __restrict__ bias,
                            const float* __restrict__ extra,
                            int K, long sA, long sB, long sD, int ldD)
{
    __shared__ _Float16 As[128 * BKK];   // 16 KB, linear
    __shared__ _Float16 Bs[128 * BKK];   // 16 KB, linear
    const int tid  = threadIdx.x;
    const int bz   = blockIdx.z;
    const int m0   = blockIdx.y * 128;
    const int n0   = blockIdx.x * 128;
    const int lane = tid & 63;
    const int wv   = tid >> 6;
    const int l15  = lane & 15;
    const int quad = lane >> 4;
    const int wm   = (wv >> 1) * 64;
    const int wn   = (wv & 1) * 64;

    f32x4 acc[4][4] = {};

    const _Float16* Ap = Abase + bz * sA + (long)m0 * K;
    const _Float16* Bp = Bbase + bz * sB + (long)n0 * K;

    for (int k0 = 0; k0 < K; k0 += BKK) {
        // A tile: 128 rows x 64 cols f16 = 16 KB = 1024 x 16B chunks; 4 issues/thread.
        // idx -> row = idx>>3, col16 = (idx&7)*8 ; LDS byte = idx*16 (lane-linear).
        #pragma unroll
        for (int it = 0; it < 4; ++it) {
            int idx = tid + it * 256;
            int r = idx >> 3, c = (idx & 7) << 3;
            gload16(Ap + (long)r * K + k0 + c, &As[idx * 8]);
        }
        #pragma unroll
        for (int it = 0; it < 4; ++it) {
            int idx = tid + it * 256;
            int r = idx >> 3, c = (idx & 7) << 3;
            gload16(Bp + (long)r * K + k0 + c, &Bs[idx * 8]);
        }
        __syncthreads();   // drains vmcnt before barrier (compiler-inserted)
        #pragma unroll
        for (int kk = 0; kk < BKK; kk += 32) {
            f16x8 af[4], bf[4];
            #pragma unroll
            for (int mt = 0; mt < 4; ++mt)
                af[mt] = *(const f16x8*)&As[(wm + mt * 16 + l15) * BKK + kk + quad * 8];
            #pragma unroll
            for (int nt = 0; nt < 4; ++nt)
                bf[nt] = *(const f16x8*)&Bs[(wn + nt * 16 + l15) * BKK + kk + quad * 8];
            #pragma unroll
            for (int mt = 0; mt < 4; ++mt)
                #pragma unroll
                for (int nt = 0; nt < 4; ++nt)
                    acc[mt][nt] = __builtin_amdgcn_mfma_f32_16x16x32_f16(af[mt], bf[nt], acc[mt][nt], 0, 0, 0);
        }
        __syncthreads();
    }

    #pragma unroll
    for (int mt = 0; mt < 4; ++mt) {
        #pragma unroll
        for (int nt = 0; nt < 4; ++nt) {
            #pragma unroll
            for (int i = 0; i < 4; ++i) {
                int row = m0 + wm + mt * 16 + quad * 4 + i;
                int col = n0 + wn + nt * 16 + l15;
                float v = acc[mt][nt][i];
                long doff = bz * sD + (long)row * ldD + col;
                if constexpr (EPI == 0) {          // h = (proj + b + te) * sqrt(1/2) -> f16
                    v = (v + bias[col] + extra[(long)row * ldD + col]) * SQRT_HALF;
                    ((_Float16*)Dbase)[doff] = (_Float16)v;
                } else if constexpr (EPI == 1) {   // raw scores -> fp32
                    ((float*)Dbase)[doff] = v;
                } else if constexpr (EPI == 2) {   // ctx * sqrt(S)=32 -> f16
                    ((_Float16*)Dbase)[doff] = (_Float16)(v * 32.0f);
                } else {                           // out = (proj + b + residual) * sqrt(1/2) -> fp32
                    v = (v + bias[col] + extra[(long)row * ldD + col]) * SQRT_HALF;
                    ((float*)Dbase)[doff] = v;
                }
            }
        }
    }
}

// ---------------- prep: KsumT[b,s,e] = enc0[b,e,s]+enc1[b,e,s]; enc2T[b,e,s] = enc2[b,s,e] ----
__global__ void prep_kernel(const float* __restrict__ enc0, const float* __restrict__ enc1,
                            const float* __restrict__ enc2,
                            _Float16* __restrict__ KsumT, _Float16* __restrict__ enc2T)
{
    __shared__ float tk[32][33];
    __shared__ float t2[32][33];
    const int b  = blockIdx.z;
    const int e0 = blockIdx.y * 32;   // E-tile
    const int s0 = blockIdx.x * 32;   // S-tile
    const int t  = threadIdx.x;
    const int r  = t >> 5;            // 0..7
    const int c  = t & 31;

    const float* p0 = enc0 + ((long)b * E_ + e0) * S_ + s0;   // rows=E, cols=S
    const float* p1 = enc1 + ((long)b * E_ + e0) * S_ + s0;
    const float* p2 = enc2 + ((long)b * S_ + s0) * E_ + e0;   // rows=S, cols=E
    #pragma unroll
    for (int rr = 0; rr < 32; rr += 8) {
        tk[r + rr][c] = p0[(long)(r + rr) * S_ + c] + p1[(long)(r + rr) * S_ + c];
        t2[r + rr][c] = p2[(long)(r + rr) * E_ + c];
    }
    __syncthreads();
    _Float16* q1 = KsumT + ((long)b * S_ + s0) * E_ + e0;     // rows=S, cols=E
    _Float16* q2 = enc2T + ((long)b * E_ + e0) * S_ + s0;     // rows=E, cols=S
    #pragma unroll
    for (int rr = 0; rr < 32; rr += 8) {
        q1[(long)(r + rr) * E_ + c] = (_Float16)tk[c][r + rr];
        q2[(long)(r + rr) * S_ + c] = (_Float16)t2[c][r + rr];
    }
}

// ---------------- x (fp32) -> xh (f16), vectorized ----------------
__global__ void cast_kernel(const float* __restrict__ src, _Float16* __restrict__ dst)
{
    long i = (((long)blockIdx.x * 256) + threadIdx.x) * 8;
    float4 a = *(const float4*)(src + i);
    float4 b = *(const float4*)(src + i + 4);
    f16x8 h;
    h[0] = (_Float16)a.x; h[1] = (_Float16)a.y; h[2] = (_Float16)a.z; h[3] = (_Float16)a.w;
    h[4] = (_Float16)b.x; h[5] = (_Float16)b.y; h[6] = (_Float16)b.z; h[7] = (_Float16)b.w;
    *(f16x8*)(dst + i) = h;
}

// ---------------- weight norm: w[o,:] = g[o] * v[o,:] / ||v[o,:]|| -> f16 ----------------
__global__ void weights_kernel(const float* __restrict__ in_v, const float* __restrict__ in_g,
                               const float* __restrict__ out_v, const float* __restrict__ out_g,
                               _Float16* __restrict__ w_in, _Float16* __restrict__ w_out)
{
    const int rowi = blockIdx.x;      // 0..1023
    const float* v; const float* g; _Float16* w; int r;
    if (rowi < E_) { r = rowi;       v = in_v  + (long)r * C_; g = in_g;  w = w_in  + (long)r * C_; }
    else           { r = rowi - E_;  v = out_v + (long)r * E_; g = out_g; w = w_out + (long)r * E_; }
    const int t = threadIdx.x;
    float a = v[t], b2 = v[t + 256];
    float ss = a * a + b2 * b2;
    #pragma unroll
    for (int off = 32; off >= 1; off >>= 1) ss += __shfl_xor(ss, off, 64);
    __shared__ float red[4];
    if ((t & 63) == 0) red[t >> 6] = ss;
    __syncthreads();
    ss = red[0] + red[1] + red[2] + red[3];
    float scale = g[r] / sqrtf(ss);
    w[t]       = (_Float16)(a * scale);
    w[t + 256] = (_Float16)(b2 * scale);
}

// ---------------- in-place row softmax over S=1024 + f16 copy ----------------
__global__ void softmax_kernel(float* __restrict__ attn, _Float16* __restrict__ attnh)
{
    const long row = blockIdx.x;
    float* p = attn + row * (long)S_;
    _Float16* ph = attnh + row * (long)S_;
    const int t = threadIdx.x;
    float4 v = *(float4*)(p + t * 4);
    float m = fmaxf(fmaxf(v.x, v.y), fmaxf(v.z, v.w));
    #pragma unroll
    for (int off = 32; off >= 1; off >>= 1) m = fmaxf(m, __shfl_xor(m, off, 64));
    __shared__ float redm[4], reds[4];
    if ((t & 63) == 0) redm[t >> 6] = m;
    __syncthreads();
    m = fmaxf(fmaxf(redm[0], redm[1]), fmaxf(redm[2], redm[3]));
    float e0 = __expf(v.x - m), e1 = __expf(v.y - m), e2 = __expf(v.z - m), e3 = __expf(v.w - m);
    float s = e0 + e1 + e2 + e3;
    #pragma unroll
    for (int off = 32; off >= 1; off >>= 1) s += __shfl_xor(s, off, 64);
    if ((t & 63) == 0) reds[t >> 6] = s;
    __syncthreads();
    s = reds[0] + reds[1] + reds[2] + reds[3];
    float inv = 1.0f / s;
    v.x = e0 * inv; v.y = e1 * inv; v.z = e2 * inv; v.w = e3 * inv;
    *(float4*)(p + t * 4) = v;
    f16x4 h;
    h[0] = (_Float16)v.x; h[1] = (_Float16)v.y; h[2] = (_Float16)v.z; h[3] = (_Float16)v.w;
    *(f16x4*)(ph + t * 4) = h;
}

extern "C" void kernel_launch(void* const* d_in, const int* in_sizes, int n_in,
                              void* d_out, int out_size, void* d_ws, size_t ws_size,
                              hipStream_t stream)
{
    (void)in_sizes; (void)n_in; (void)out_size; (void)ws_size;
    const float* x     = (const float*)d_in[0];   // [B,T,C]
    const float* te    = (const float*)d_in[1];   // [B,T,E]
    const float* enc0  = (const float*)d_in[2];   // [B,E,S]
    const float* enc1  = (const float*)d_in[3];   // [B,E,S]
    const float* enc2  = (const float*)d_in[4];   // [B,S,E]
    const float* in_v  = (const float*)d_in[5];   // [E,C]
    const float* in_g  = (const float*)d_in[6];
    const float* in_b  = (const float*)d_in[7];
    const float* out_v = (const float*)d_in[8];   // [C,E]
    const float* out_g = (const float*)d_in[9];
    const float* out_b = (const float*)d_in[10];

    float* out  = (float*)d_out;                  // [B*T, C] fp32
    float* attn = out + (long)B_ * T_ * C_;       // [B, T, S] fp32 (scores in-place -> softmax)

    // Workspace layout (269,484,032 B total — same footprint as before, lifetime-aliased):
    //   w_in, w_out, KsumT(=ctxb after step 5), enc2T, xh, hbuf
    //   attnh (134 MB) = xh+hbuf region (both dead after step 5)
    //   ctxb  ( 67 MB) = KsumT region (dead after step 5)
    _Float16* w_in  = (_Float16*)d_ws;
    _Float16* w_out = w_in  + (long)E_ * C_;
    _Float16* KsumT = w_out + (long)C_ * E_;      // [B, S, E] f16
    _Float16* enc2T = KsumT + (long)B_ * S_ * E_; // [B, E, S] f16
    _Float16* xh    = enc2T + (long)B_ * E_ * S_; // [B*T, C] f16
    _Float16* hbuf  = xh    + (long)B_ * T_ * C_; // [B*T, E] f16
    _Float16* attnh = xh;                         // [B, T, S] f16  (aliases xh+hbuf)
    _Float16* ctxb  = KsumT;                      // [B*T, E] f16  (aliases KsumT)

    // 1) transpose/add/cast encoder tensors
    prep_kernel<<<dim3(S_ / 32, E_ / 32, B_), 256, 0, stream>>>(enc0, enc1, enc2, KsumT, enc2T);
    // 2) weight-normalized matrices -> f16
    weights_kernel<<<dim3(E_ + C_), 256, 0, stream>>>(in_v, in_g, out_v, out_g, w_in, w_out);
    // 2b) x -> f16
    cast_kernel<<<dim3((B_ * T_ * C_) / (256 * 8)), 256, 0, stream>>>(x, xh);
    // 3) h = (x @ w_in^T + in_b + te) * sqrt(1/2)   M=65536 N=512 K=512
    gemm_kernel<0><<<dim3(E_ / 128, (B_ * T_) / 128, 1), 256, 0, stream>>>(
        xh, w_in, hbuf, in_b, te, C_, 0, 0, 0, E_);
    // 4) scores[b] = h[b] @ KsumT[b]^T  -> fp32 into attn slot   M=T N=S K=E per batch
    gemm_kernel<1><<<dim3(S_ / 128, T_ / 128, B_), 256, 0, stream>>>(
        hbuf, KsumT, attn, nullptr, nullptr, E_,
        (long)T_ * E_, (long)S_ * E_, (long)T_ * S_, S_);
    // 5) softmax rows in place + f16 copy for the PV GEMM
    softmax_kernel<<<dim3(B_ * T_), 256, 0, stream>>>(attn, attnh);
    // 6) ctx[b] = attn[b] @ enc2T[b]^T * 32 -> f16   M=T N=E K=S per batch
    gemm_kernel<2><<<dim3(E_ / 128, T_ / 128, B_), 256, 0, stream>>>(
        attnh, enc2T, ctxb, nullptr, nullptr, S_,
        (long)T_ * S_, (long)E_ * S_, (long)T_ * E_, E_);
    // 7) out = (ctx @ w_out^T + out_b + x) * sqrt(1/2) -> fp32   M=65536 N=512 K=512
    gemm_kernel<3><<<dim3(C_ / 128, (B_ * T_) / 128, 1), 256, 0, stream>>>(
        ctxb, w_out, out, out_b, x, E_, 0, 0, 0, C_);
}